// Round 12
// baseline (455.776 us; speedup 1.0000x reference)
//
#include <hip/hip_runtime.h>
#include <math.h>

#define NG 256
#define NBK 512          // sort buckets
#define BCAP 3584        // per-bucket staging capacity (mean 3125, +8 sigma)
#define FBN 96           // nodes per fused layer23 block (52KB LDS, 3 blocks/CU)
// Measured design space (do not revisit): FBN96/fp32-z2 = 94us BEST structure;
// FBN64 = 111us (ILP cut); bf16-z2 4blk/CU = 105us (L2 thrash);
// gather/transform SPLIT = 97us transform alone; global-atomic pool = 5x worse.
// This round: gather MLP 8->16 outstanding loads (latency-bound identity:
// 12 waves x 8 loads x 32B / 500cy = 1.05 TB/s == measured).

static __device__ __forceinline__ int bucket_lo(int p, int n) {
    return (int)(((long long)p * n + NBK - 1) / NBK);   // ceil(p*n/NBK)
}

// ---- bf16 helpers (tables stored as packed pairs in uint) ----
static __device__ __forceinline__ float blo(unsigned u) {
    return __uint_as_float(u << 16);
}
static __device__ __forceinline__ float bhi(unsigned u) {
    return __uint_as_float(u & 0xFFFF0000u);
}
static __device__ __forceinline__ unsigned packbf(float a, float b) {
    unsigned ua = __float_as_uint(a);
    ua = (ua + 0x7FFFu + ((ua >> 16) & 1u)) >> 16;          // RNE, low half
    unsigned ub = __float_as_uint(b);
    ub = (ub + 0x7FFFu + ((ub >> 16) & 1u)) & 0xFFFF0000u;  // RNE, high half
    return ua | ub;
}

// ---------------- bucket cursor init ----------------
__global__ void zero_bcur(int* bcur) {
    int i = blockIdx.x * blockDim.x + threadIdx.x;
    if (i < NBK) bcur[i] = i * BCAP;
}

// ------- phase A: bucket edges by dst; staged record = (src<<8)|local_dst --
__global__ void bucketA(const int* __restrict__ src, const int* __restrict__ dst,
                        int* bcur, unsigned* stage, int e, int n) {
    __shared__ int cnt[NBK];
    __shared__ int base[NBK];
    int nb = gridDim.x;
    int c0 = (int)((long long)blockIdx.x * e / nb);
    int c1 = (int)((long long)(blockIdx.x + 1) * e / nb);
    for (int k = threadIdx.x; k < NBK; k += blockDim.x) cnt[k] = 0;
    __syncthreads();
    for (int i = c0 + threadIdx.x; i < c1; i += blockDim.x) {
        int d = dst[i];
        int p = (int)((long long)d * NBK / n);
        atomicAdd(&cnt[p], 1);
    }
    __syncthreads();
    for (int k = threadIdx.x; k < NBK; k += blockDim.x)
        base[k] = atomicAdd(&bcur[k], cnt[k]);
    __syncthreads();
    for (int k = threadIdx.x; k < NBK; k += blockDim.x) cnt[k] = 0;
    __syncthreads();
    for (int i = c0 + threadIdx.x; i < c1; i += blockDim.x) {
        int s = src[i], d = dst[i];
        int p = (int)((long long)d * NBK / n);
        int ldst = d - bucket_lo(p, n);           // < 196, fits 8 bits
        int lp = atomicAdd(&cnt[p], 1);
        stage[base[p] + lp] = ((unsigned)s << 8) | (unsigned)ldst;
    }
}

// ======= fused CSR finish: hist + scan + rowptr + dinv + xs + scatter ====
// xs rows padded to 8 floats (32B): one aligned 64B-line touch per gather.
__global__ void fillB2(const unsigned* __restrict__ stage,
                       const int* __restrict__ bcur,
                       int* __restrict__ rowptr, float* __restrict__ dinv,
                       int* __restrict__ csrs,
                       const float* __restrict__ x, float* __restrict__ xs,
                       int n, int e) {
    __shared__ int ldeg[256];
    __shared__ int loff[256];
    __shared__ int bstart;
    int p = blockIdx.x;
    int t = threadIdx.x;
    int lo = bucket_lo(p, n), hi = bucket_lo(p + 1, n);
    int nloc = hi - lo;                           // <= 196

    // ---- bucketStart[p] = sum of counts of buckets < p ----
    {
        int acc = 0;
        for (int k = t; k < p; k += 256) acc += bcur[k] - k * BCAP;
        ldeg[t] = acc;
        __syncthreads();
        for (int off = 128; off > 0; off >>= 1) {
            if (t < off) ldeg[t] += ldeg[t + off];
            __syncthreads();
        }
        if (t == 0) bstart = ldeg[0];
        __syncthreads();
    }

    // ---- local degree histogram ----
    if (t < 256) ldeg[t] = 0;
    __syncthreads();
    int s0 = p * BCAP, s1 = bcur[p];
    for (int i = s0 + t; i < s1; i += 256)
        atomicAdd(&ldeg[stage[i] & 255u], 1);
    __syncthreads();

    // ---- exclusive scan (256-wide) -> rowptr, dinv, xs, cursors ----
    int v = (t < nloc) ? ldeg[t] : 0;
    loff[t] = v;
    __syncthreads();
    for (int off = 1; off < 256; off <<= 1) {
        int u = (t >= off) ? loff[t - off] : 0;
        __syncthreads();
        loff[t] += u;
        __syncthreads();
    }
    if (t < nloc) {
        int start = bstart + loff[t] - v;         // exclusive
        rowptr[lo + t] = start;
        float dv = rsqrtf((float)v + 1.0f);       // +1 self-loop
        dinv[lo + t] = dv;
        // dinv-folded source rows for layer-1 gather (32B-padded rows)
        const float* xr = x + (size_t)(lo + t) * 5;
        float* xo = xs + (size_t)(lo + t) * 8;
#pragma unroll
        for (int k = 0; k < 5; ++k) xo[k] = xr[k] * dv;
    }
    if (p == NBK - 1 && t == 0) rowptr[n] = e;
    __syncthreads();
    if (t < nloc) ldeg[t] = bstart + loff[t] - v; // reuse as cursors
    __syncthreads();

    // ---- scatter ----
    for (int i = s0 + t; i < s1; i += 256) {
        unsigned pk = stage[i];
        int ldst = (int)(pk & 255u);
        int pos = atomicAdd(&ldeg[ldst], 1);
        csrs[pos] = (int)(pk >> 8);
    }
}

// ---------------- layer-1 aggregate on dinv-folded xs (5-dim, 8-stride) --
// 8-deep batches (16 outstanding loads), masked tail
__global__ void gather5(const int* __restrict__ rowptr,
                        const int* __restrict__ csrs,
                        const float* __restrict__ dinv,
                        const float* __restrict__ xs,
                        float* __restrict__ z, int n) {
    int i = blockIdx.x * blockDim.x + threadIdx.x;
    if (i >= n) return;
    const float* xr = xs + (size_t)i * 8;
    float4 x4 = *(const float4*)(xr);
    float a0 = x4.x, a1 = x4.y, a2 = x4.z, a3 = x4.w, a4 = xr[4];
    int j = rowptr[i], end = rowptr[i + 1], e1 = end - 1;
    for (; j < end; j += 8) {
        int s[8]; float m[8];
#pragma unroll
        for (int k = 0; k < 8; ++k) {
            int jj = j + k;
            s[k] = csrs[jj <= e1 ? jj : e1];
            m[k] = (jj < end) ? 1.0f : 0.0f;
        }
        float4 r4[8]; float r1[8];
#pragma unroll
        for (int k = 0; k < 8; ++k) {
            const float* r = xs + (size_t)s[k] * 8;
            r4[k] = *(const float4*)(r);
            r1[k] = r[4];
        }
#pragma unroll
        for (int k = 0; k < 8; ++k) {
            a0 = fmaf(m[k], r4[k].x, a0);
            a1 = fmaf(m[k], r4[k].y, a1);
            a2 = fmaf(m[k], r4[k].z, a2);
            a3 = fmaf(m[k], r4[k].w, a3);
            a4 = fmaf(m[k], r1[k], a4);
        }
    }
    float di = dinv[i];
    float* zr = z + (size_t)i * 5;
    zr[0] = a0 * di; zr[1] = a1 * di; zr[2] = a2 * di;
    zr[3] = a3 * di; zr[4] = a4 * di;
}

// ---- transform epilogue: bias/relu/scale + fp32 or packed-bf16 store ----
template<int DOUT, bool BR, bool SCALE, bool OUTBF>
static __device__ __forceinline__ void emit(float o[8], const float* b, int c,
                                            float dsc, void* out, int i) {
    if (BR) {
        float4 b0 = *(const float4*)(b + c * 8);
        float4 b1 = *(const float4*)(b + c * 8 + 4);
        o[0] = fmaxf(o[0] + b0.x, 0.f); o[1] = fmaxf(o[1] + b0.y, 0.f);
        o[2] = fmaxf(o[2] + b0.z, 0.f); o[3] = fmaxf(o[3] + b0.w, 0.f);
        o[4] = fmaxf(o[4] + b1.x, 0.f); o[5] = fmaxf(o[5] + b1.y, 0.f);
        o[6] = fmaxf(o[6] + b1.z, 0.f); o[7] = fmaxf(o[7] + b1.w, 0.f);
    }
    if (SCALE) {
#pragma unroll
        for (int q = 0; q < 8; ++q) o[q] *= dsc;
    }
    if (OUTBF) {
        uint4 pk;
        pk.x = packbf(o[0], o[1]); pk.y = packbf(o[2], o[3]);
        pk.z = packbf(o[4], o[5]); pk.w = packbf(o[6], o[7]);
        *(uint4*)((unsigned*)out + (size_t)i * (DOUT / 2) + c * 4) = pk;
    } else {
        float* op = (float*)out + (size_t)i * DOUT + c * 8;
        float4 o0 = {o[0], o[1], o[2], o[3]};
        float4 o1 = {o[4], o[5], o[6], o[7]};
        *(float4*)(op) = o0;
        *(float4*)(op + 4) = o1;
    }
}

// ---- K=5 fp32-input transform (layer 1) --------------------------------
template<int DOUT, bool BR, bool SCALE, bool OUTBF, int NODES>
__global__ void transformB5(const float* __restrict__ xin,
                            const float* __restrict__ W,
                            const float* __restrict__ b,
                            const float* __restrict__ dinv,
                            void* __restrict__ out, int n) {
    const int C = DOUT / 8;
    int tid = blockIdx.x * blockDim.x + threadIdx.x;
    int grp = tid / C;
    int c = tid % C;
    int i0 = grp * NODES;
    if (i0 >= n) return;
    float r[NODES][5];
#pragma unroll
    for (int nn = 0; nn < NODES; ++nn) {
        int idx = i0 + nn < n ? i0 + nn : n - 1;
        const float* row = xin + (size_t)idx * 5;
#pragma unroll
        for (int k = 0; k < 5; ++k) r[nn][k] = row[k];
    }
    float acc[NODES][8];
#pragma unroll
    for (int nn = 0; nn < NODES; ++nn)
#pragma unroll
        for (int q = 0; q < 8; ++q) acc[nn][q] = 0.0f;
#pragma unroll
    for (int k = 0; k < 5; ++k) {
        const float* wp = W + (size_t)k * DOUT + c * 8;
        float4 w0 = *(const float4*)(wp);
        float4 w1 = *(const float4*)(wp + 4);
#pragma unroll
        for (int nn = 0; nn < NODES; ++nn) {
            float v = r[nn][k];
            acc[nn][0] = fmaf(v, w0.x, acc[nn][0]);
            acc[nn][1] = fmaf(v, w0.y, acc[nn][1]);
            acc[nn][2] = fmaf(v, w0.z, acc[nn][2]);
            acc[nn][3] = fmaf(v, w0.w, acc[nn][3]);
            acc[nn][4] = fmaf(v, w1.x, acc[nn][4]);
            acc[nn][5] = fmaf(v, w1.y, acc[nn][5]);
            acc[nn][6] = fmaf(v, w1.z, acc[nn][6]);
            acc[nn][7] = fmaf(v, w1.w, acc[nn][7]);
        }
    }
#pragma unroll
    for (int nn = 0; nn < NODES; ++nn) {
        if (i0 + nn >= n) break;
        float dsc = SCALE ? dinv[i0 + nn] : 1.0f;
        emit<DOUT, BR, SCALE, OUTBF>(acc[nn], b, c, dsc, out, i0 + nn);
    }
}

// ------- 64-dim gather from bf16 table (dinv pre-folded into table) ------
// 16 outstanding row loads (latency-bound: BW scales with loads in flight)
static __device__ __forceinline__ void gather_row(const int* __restrict__ rowptr,
                                                  const int* __restrict__ csrs,
                                                  const unsigned* __restrict__ g,
                                                  int i, int c, float o[8]) {
    uint4 sv = *(const uint4*)(g + (size_t)i * 32 + c * 4);
    float a[4][8];
#pragma unroll
    for (int q = 0; q < 8; ++q) { a[1][q] = 0.f; a[2][q] = 0.f; a[3][q] = 0.f; }
    a[0][0] = blo(sv.x); a[0][1] = bhi(sv.x); a[0][2] = blo(sv.y); a[0][3] = bhi(sv.y);
    a[0][4] = blo(sv.z); a[0][5] = bhi(sv.z); a[0][6] = blo(sv.w); a[0][7] = bhi(sv.w);
    int j = rowptr[i], end = rowptr[i + 1];
    for (; j + 16 <= end; j += 16) {
        uint4 v[16];
#pragma unroll
        for (int k = 0; k < 16; ++k)
            v[k] = *(const uint4*)(g + (size_t)csrs[j + k] * 32 + c * 4);
#pragma unroll
        for (int k = 0; k < 16; ++k) {
            float* aa = a[k & 3];
            aa[0] += blo(v[k].x); aa[1] += bhi(v[k].x);
            aa[2] += blo(v[k].y); aa[3] += bhi(v[k].y);
            aa[4] += blo(v[k].z); aa[5] += bhi(v[k].z);
            aa[6] += blo(v[k].w); aa[7] += bhi(v[k].w);
        }
    }
    if (j < end) {
        int e1 = end - 1;
        uint4 v[16]; float mm[16];
#pragma unroll
        for (int k = 0; k < 16; ++k) {
            int jj = j + k;
            int sx = csrs[jj <= e1 ? jj : e1];
            mm[k] = (jj < end) ? 1.0f : 0.0f;
            v[k] = *(const uint4*)(g + (size_t)sx * 32 + c * 4);
        }
#pragma unroll
        for (int k = 0; k < 16; ++k) {
            float* aa = a[k & 3];
            float m = mm[k];
            aa[0] = fmaf(m, blo(v[k].x), aa[0]); aa[1] = fmaf(m, bhi(v[k].x), aa[1]);
            aa[2] = fmaf(m, blo(v[k].y), aa[2]); aa[3] = fmaf(m, bhi(v[k].y), aa[3]);
            aa[4] = fmaf(m, blo(v[k].z), aa[4]); aa[5] = fmaf(m, bhi(v[k].z), aa[5]);
            aa[6] = fmaf(m, blo(v[k].w), aa[6]); aa[7] = fmaf(m, bhi(v[k].w), aa[7]);
        }
    }
#pragma unroll
    for (int q = 0; q < 8; ++q)
        o[q] = (a[0][q] + a[1][q]) + (a[2][q] + a[3][q]);
}

// BR: +bias+relu.  OUTBF: pack bf16 rows [n][32]; else fp32 [n][64].
template<bool BR, bool OUTBF>
__global__ void gatherBF(const int* __restrict__ rowptr,
                         const int* __restrict__ csrs,
                         const float* __restrict__ dinv,
                         const float* __restrict__ b,
                         const unsigned* __restrict__ g,   // [n][32] packed bf16
                         void* __restrict__ z, int n) {
    int tid = blockIdx.x * blockDim.x + threadIdx.x;
    int i = tid >> 3;
    int c = tid & 7;
    if (i >= n) return;
    float o[8];
    gather_row(rowptr, csrs, g, i, c, o);
    float di = dinv[i];
#pragma unroll
    for (int q = 0; q < 8; ++q) o[q] *= di;
    if (BR) {
        float4 b0 = *(const float4*)(b + c * 8);
        float4 b1 = *(const float4*)(b + c * 8 + 4);
        o[0] = fmaxf(o[0] + b0.x, 0.f); o[1] = fmaxf(o[1] + b0.y, 0.f);
        o[2] = fmaxf(o[2] + b0.z, 0.f); o[3] = fmaxf(o[3] + b0.w, 0.f);
        o[4] = fmaxf(o[4] + b1.x, 0.f); o[5] = fmaxf(o[5] + b1.y, 0.f);
        o[6] = fmaxf(o[6] + b1.z, 0.f); o[7] = fmaxf(o[7] + b1.w, 0.f);
    }
    if (OUTBF) {
        uint4 pk;
        pk.x = packbf(o[0], o[1]); pk.y = packbf(o[2], o[3]);
        pk.z = packbf(o[4], o[5]); pk.w = packbf(o[6], o[7]);
        *(uint4*)((unsigned*)z + (size_t)i * 32 + c * 4) = pk;
    } else {
        float* zp = (float*)z + (size_t)i * 64 + c * 8;
        float4 z0 = {o[0], o[1], o[2], o[3]};
        float4 z1 = {o[4], o[5], o[6], o[7]};
        *(float4*)(zp) = z0;
        *(float4*)(zp + 4) = z1;
    }
}

// ===== fused layer-2+3: gather(h1bf)->z2(LDS,fp32) ->W2+b2+relu->
//       h2(LDS,bf16) ->W3*dinv -> t3bf.  96 nodes / 256 threads. =====
__global__ void layer23(const int* __restrict__ rowptr,
                        const int* __restrict__ csrs,
                        const float* __restrict__ dinv,
                        const float* __restrict__ b2v,
                        const unsigned* __restrict__ g,    // h1bf [n][32]
                        const float* __restrict__ W2,      // [64][128]
                        const float* __restrict__ W3,      // [128][64]
                        unsigned* __restrict__ t3, int n) {
    __shared__ float    z2s[FBN][68];   // fp32, stride 68 (quad-stride 17)
    __shared__ unsigned h2s[FBN][68];   // 64 uints bf16 + pad
    int t = threadIdx.x;
    int base = blockIdx.x * FBN;

    // ---- phase 1: gather z2 rows; 3 passes x 32 nodes, 8 lanes/node ----
    {
        int nd = t >> 3, c = t & 7;
        for (int pass = 0; pass < 3; ++pass) {
            int lr = pass * 32 + nd;
            int i = base + lr;
            if (i < n) {
                float o[8];
                gather_row(rowptr, csrs, g, i, c, o);
                float di = dinv[i];
                float4 z0 = {o[0] * di, o[1] * di, o[2] * di, o[3] * di};
                float4 z1 = {o[4] * di, o[5] * di, o[6] * di, o[7] * di};
                *(float4*)&z2s[lr][c * 8] = z0;
                *(float4*)&z2s[lr][c * 8 + 4] = z1;
            }
        }
    }
    __syncthreads();

    // ---- phase 2: 64->128 + bias + relu -> bf16 h2s (6 nodes/thread) ----
    {
        int c2 = t & 15;             // outs c2*8..+8 (of 128)
        int ng = t >> 4;             // 0..15; nodes ng + 16*nn
        float acc[6][8];
#pragma unroll
        for (int nn = 0; nn < 6; ++nn)
#pragma unroll
            for (int q = 0; q < 8; ++q) acc[nn][q] = 0.0f;
        for (int k0 = 0; k0 < 64; k0 += 4) {
            float4 r[6];
#pragma unroll
            for (int nn = 0; nn < 6; ++nn)
                r[nn] = *(const float4*)&z2s[ng + 16 * nn][k0];
#pragma unroll
            for (int kk = 0; kk < 4; ++kk) {
                const float* wp = W2 + (size_t)(k0 + kk) * 128 + c2 * 8;
                float4 w0 = *(const float4*)(wp);
                float4 w1 = *(const float4*)(wp + 4);
#pragma unroll
                for (int nn = 0; nn < 6; ++nn) {
                    float v = (&r[nn].x)[kk];
                    acc[nn][0] = fmaf(v, w0.x, acc[nn][0]);
                    acc[nn][1] = fmaf(v, w0.y, acc[nn][1]);
                    acc[nn][2] = fmaf(v, w0.z, acc[nn][2]);
                    acc[nn][3] = fmaf(v, w0.w, acc[nn][3]);
                    acc[nn][4] = fmaf(v, w1.x, acc[nn][4]);
                    acc[nn][5] = fmaf(v, w1.y, acc[nn][5]);
                    acc[nn][6] = fmaf(v, w1.z, acc[nn][6]);
                    acc[nn][7] = fmaf(v, w1.w, acc[nn][7]);
                }
            }
        }
        float4 b0 = *(const float4*)(b2v + c2 * 8);
        float4 b1 = *(const float4*)(b2v + c2 * 8 + 4);
#pragma unroll
        for (int nn = 0; nn < 6; ++nn) {
            float o[8];
            o[0] = fmaxf(acc[nn][0] + b0.x, 0.f);
            o[1] = fmaxf(acc[nn][1] + b0.y, 0.f);
            o[2] = fmaxf(acc[nn][2] + b0.z, 0.f);
            o[3] = fmaxf(acc[nn][3] + b0.w, 0.f);
            o[4] = fmaxf(acc[nn][4] + b1.x, 0.f);
            o[5] = fmaxf(acc[nn][5] + b1.y, 0.f);
            o[6] = fmaxf(acc[nn][6] + b1.z, 0.f);
            o[7] = fmaxf(acc[nn][7] + b1.w, 0.f);
            uint4 pk;
            pk.x = packbf(o[0], o[1]); pk.y = packbf(o[2], o[3]);
            pk.z = packbf(o[4], o[5]); pk.w = packbf(o[6], o[7]);
            *(uint4*)&h2s[ng + 16 * nn][c2 * 4] = pk;
        }
    }
    __syncthreads();

    // ---- phase 3: bf16 128->64, *dinv -> t3 (3 nodes/thread) ----
    {
        int c3 = t & 7;              // outs c3*8..+8 (of 64)
        int ng = t >> 3;             // 0..31; nodes ng + 32*nn
        float acc[3][8];
#pragma unroll
        for (int nn = 0; nn < 3; ++nn)
#pragma unroll
            for (int q = 0; q < 8; ++q) acc[nn][q] = 0.0f;
        for (int k0 = 0; k0 < 128; k0 += 8) {
            uint4 r[3];
#pragma unroll
            for (int nn = 0; nn < 3; ++nn)
                r[nn] = *(const uint4*)&h2s[ng + 32 * nn][k0 >> 1];
#pragma unroll
            for (int kk = 0; kk < 8; ++kk) {
                const float* wp = W3 + (size_t)(k0 + kk) * 64 + c3 * 8;
                float4 w0 = *(const float4*)(wp);
                float4 w1 = *(const float4*)(wp + 4);
#pragma unroll
                for (int nn = 0; nn < 3; ++nn) {
                    unsigned u = (&r[nn].x)[kk >> 1];
                    float v = (kk & 1) ? bhi(u) : blo(u);
                    acc[nn][0] = fmaf(v, w0.x, acc[nn][0]);
                    acc[nn][1] = fmaf(v, w0.y, acc[nn][1]);
                    acc[nn][2] = fmaf(v, w0.z, acc[nn][2]);
                    acc[nn][3] = fmaf(v, w0.w, acc[nn][3]);
                    acc[nn][4] = fmaf(v, w1.x, acc[nn][4]);
                    acc[nn][5] = fmaf(v, w1.y, acc[nn][5]);
                    acc[nn][6] = fmaf(v, w1.z, acc[nn][6]);
                    acc[nn][7] = fmaf(v, w1.w, acc[nn][7]);
                }
            }
        }
#pragma unroll
        for (int nn = 0; nn < 3; ++nn) {
            int i = base + ng + 32 * nn;
            if (i < n) {
                float ds = dinv[i];
                uint4 pk;
                pk.x = packbf(acc[nn][0] * ds, acc[nn][1] * ds);
                pk.y = packbf(acc[nn][2] * ds, acc[nn][3] * ds);
                pk.z = packbf(acc[nn][4] * ds, acc[nn][5] * ds);
                pk.w = packbf(acc[nn][6] * ds, acc[nn][7] * ds);
                *(uint4*)(t3 + (size_t)i * 32 + c3 * 4) = pk;
            }
        }
    }
}

// ------- pooling + FC + sigmoid: 4 waves per graph, bf16 h3 rows --------
__global__ void pool(const unsigned* __restrict__ h3,  // [n][32] packed bf16
                     const int* __restrict__ batch,
                     const float* __restrict__ Wfc, const float* __restrict__ bfc,
                     float* __restrict__ out, int n) {
    int g = blockIdx.x;
    int lane = threadIdx.x & 63;
    int w = threadIdx.x >> 6;  // 0..3
    int lo = 0, hi = n;
    while (lo < hi) { int m = (lo + hi) >> 1; if (batch[m] < g) lo = m + 1; else hi = m; }
    int start = lo;
    hi = n;
    while (lo < hi) { int m = (lo + hi) >> 1; if (batch[m] < g + 1) lo = m + 1; else hi = m; }
    int end = lo;
    int ui = lane >> 1;            // uint index within row
    bool hs = lane & 1;            // hi/lo half
    float a0 = 0.f, a1 = 0.f, a2 = 0.f, a3 = 0.f;
    int m = start + w;
    for (; m + 12 < end; m += 16) {
        unsigned u0 = h3[(size_t)m * 32 + ui];
        unsigned u1 = h3[(size_t)(m + 4) * 32 + ui];
        unsigned u2 = h3[(size_t)(m + 8) * 32 + ui];
        unsigned u3 = h3[(size_t)(m + 12) * 32 + ui];
        a0 += hs ? bhi(u0) : blo(u0);
        a1 += hs ? bhi(u1) : blo(u1);
        a2 += hs ? bhi(u2) : blo(u2);
        a3 += hs ? bhi(u3) : blo(u3);
    }
    for (; m < end; m += 4) {
        unsigned u0 = h3[(size_t)m * 32 + ui];
        a0 += hs ? bhi(u0) : blo(u0);
    }
    __shared__ float sh[4][64];
    sh[w][lane] = (a0 + a1) + (a2 + a3);
    __syncthreads();
    if (w == 0) {
        float v = (sh[0][lane] + sh[1][lane]) + (sh[2][lane] + sh[3][lane]);
        float cnt = (float)(end - start);
        v = (v / fmaxf(cnt, 1.0f)) * Wfc[lane];
#pragma unroll
        for (int off = 32; off > 0; off >>= 1) v += __shfl_down(v, off, 64);
        if (lane == 0) out[g] = 1.0f / (1.0f + expf(-(v + bfc[0])));
    }
}

static inline int cdiv(long long a, int b) { return (int)((a + b - 1) / b); }

extern "C" void kernel_launch(void* const* d_in, const int* in_sizes, int n_in,
                              void* d_out, int out_size, void* d_ws, size_t ws_size,
                              hipStream_t stream) {
    const float* x   = (const float*)d_in[0];
    const int*   ei  = (const int*)d_in[1];
    const int*   bat = (const int*)d_in[2];
    const float* W1  = (const float*)d_in[3];
    const float* b1  = (const float*)d_in[4];
    const float* W2  = (const float*)d_in[5];
    const float* b2  = (const float*)d_in[6];
    const float* W3  = (const float*)d_in[7];
    const float* b3  = (const float*)d_in[8];
    const float* Wfc = (const float*)d_in[9];
    const float* bfc = (const float*)d_in[10];
    float* out = (float*)d_out;

    const int N = in_sizes[0] / 5;   // 100000
    const int E = in_sizes[1] / 2;   // 1600000
    const int* src = ei;
    const int* ds  = ei + E;

    // ---- workspace layout: every buffer 256B-aligned so bf16 feature
    //      rows (128B) never straddle cache lines on random gathers ----
    char* wsb = (char*)d_ws;
    size_t off = 0;
#define A256(X) (((X) + (size_t)255) & ~(size_t)255)
    float* dinv   = (float*)(wsb + off); off = A256(off + (size_t)N * 4);
    int*   rowptr = (int*)(wsb + off);   off = A256(off + (size_t)(N + 4) * 4);
    int*   bcur   = (int*)(wsb + off);   off = A256(off + (size_t)NBK * 4);
    int*   csrs   = (int*)(wsb + off);   off = A256(off + (size_t)E * 4);
    float* A      = (float*)(wsb + off); off = A256(off + (size_t)N * 128 * 4);
    float* B      = (float*)(wsb + off);
#undef A256
    // aliases (strictly sequential lifetimes):
    unsigned* stage = (unsigned*)A;              // 7.34MB, dead after fillB2
    float*    xs    = A + (size_t)(1 << 21);     // N*8 fp32 @ +8MB (past stage)
    float*    z1    = A;                         // N*5 fp32 (disjoint from xs)
    unsigned* h1bf  = (unsigned*)B;              // N*32 (bf16, dinv-folded)
    unsigned* t3bf  = (unsigned*)A;              // N*32 bf16 (z1/xs dead)
    unsigned* h3bf  = (unsigned*)B;              // N*32 bf16 (h1bf dead)

    const int Blk = 256;

    // ---- CSR build: bucket sort -> fused hist/scan/dinv/xs/scatter ----
    zero_bcur<<<2, 256, 0, stream>>>(bcur);
    bucketA<<<256, 256, 0, stream>>>(src, ds, bcur, stage, E, N);
    fillB2<<<NBK, 256, 0, stream>>>(stage, bcur, rowptr, dinv, csrs, x, xs, N, E);

    // ---- layer 1: aggregate folded xs (5-dim); 5->64 +bias+relu ->bf16*dinv
    gather5<<<cdiv(N, Blk), Blk, 0, stream>>>(rowptr, csrs, dinv, xs, z1, N);
    transformB5<64, true, true, true, 2>
        <<<cdiv((long long)cdiv(N, 2) * 8, Blk), Blk, 0, stream>>>(
        z1, W1, b1, dinv, h1bf, N);

    // ---- fused layers 2+3: gather->T2(relu)->T3(*dinv) -> t3bf ----
    layer23<<<cdiv(N, FBN), 256, 0, stream>>>(
        rowptr, csrs, dinv, b2, h1bf, W2, W3, t3bf, N);

    // ---- layer 3 aggregate: gather t3bf +bias+relu -> bf16 h3 ----
    gatherBF<true, true><<<cdiv((long long)N * 8, Blk), Blk, 0, stream>>>(
        rowptr, csrs, dinv, b3, t3bf, h3bf, N);

    // ---- pooling + FC head ----
    pool<<<NG, 256, 0, stream>>>(h3bf, bat, Wfc, bfc, out, N);
}

// Round 13
// 293.428 us; speedup vs baseline: 1.5533x; 1.5533x over previous
//
#include <hip/hip_runtime.h>
#include <math.h>

#define NG 256
#define NBK 512          // sort buckets
#define BCAP 3584        // per-bucket staging capacity (mean 3125, +8 sigma)
#define FBN 96           // nodes per fused layer23 block (52KB LDS, 3 blocks/CU)
// Measured design space (do not revisit): FBN96/fp32-z2 = 94us BEST structure;
// FBN64 = 111us (ILP cut); bf16-z2 4blk/CU = 105us (L2 thrash);
// gather/transform SPLIT = 97us; global-atomic pool = 5x worse.
// R12: 16-deep gather WITHOUT launch_bounds -> compiler kept 64 VGPR and
// SPILLED (WRITE 12.5->177MB, 188us). This round: same 16-deep + explicit
// __launch_bounds__ so the allocator may use ~130 VGPRs (no occupancy cost:
// layer23 is LDS-capped at 3 blk/CU anyway).

static __device__ __forceinline__ int bucket_lo(int p, int n) {
    return (int)(((long long)p * n + NBK - 1) / NBK);   // ceil(p*n/NBK)
}

// ---- bf16 helpers (tables stored as packed pairs in uint) ----
static __device__ __forceinline__ float blo(unsigned u) {
    return __uint_as_float(u << 16);
}
static __device__ __forceinline__ float bhi(unsigned u) {
    return __uint_as_float(u & 0xFFFF0000u);
}
static __device__ __forceinline__ unsigned packbf(float a, float b) {
    unsigned ua = __float_as_uint(a);
    ua = (ua + 0x7FFFu + ((ua >> 16) & 1u)) >> 16;          // RNE, low half
    unsigned ub = __float_as_uint(b);
    ub = (ub + 0x7FFFu + ((ub >> 16) & 1u)) & 0xFFFF0000u;  // RNE, high half
    return ua | ub;
}

// ---------------- bucket cursor init ----------------
__global__ void zero_bcur(int* bcur) {
    int i = blockIdx.x * blockDim.x + threadIdx.x;
    if (i < NBK) bcur[i] = i * BCAP;
}

// ------- phase A: bucket edges by dst; staged record = (src<<8)|local_dst --
__global__ void bucketA(const int* __restrict__ src, const int* __restrict__ dst,
                        int* bcur, unsigned* stage, int e, int n) {
    __shared__ int cnt[NBK];
    __shared__ int base[NBK];
    int nb = gridDim.x;
    int c0 = (int)((long long)blockIdx.x * e / nb);
    int c1 = (int)((long long)(blockIdx.x + 1) * e / nb);
    for (int k = threadIdx.x; k < NBK; k += blockDim.x) cnt[k] = 0;
    __syncthreads();
    for (int i = c0 + threadIdx.x; i < c1; i += blockDim.x) {
        int d = dst[i];
        int p = (int)((long long)d * NBK / n);
        atomicAdd(&cnt[p], 1);
    }
    __syncthreads();
    for (int k = threadIdx.x; k < NBK; k += blockDim.x)
        base[k] = atomicAdd(&bcur[k], cnt[k]);
    __syncthreads();
    for (int k = threadIdx.x; k < NBK; k += blockDim.x) cnt[k] = 0;
    __syncthreads();
    for (int i = c0 + threadIdx.x; i < c1; i += blockDim.x) {
        int s = src[i], d = dst[i];
        int p = (int)((long long)d * NBK / n);
        int ldst = d - bucket_lo(p, n);           // < 196, fits 8 bits
        int lp = atomicAdd(&cnt[p], 1);
        stage[base[p] + lp] = ((unsigned)s << 8) | (unsigned)ldst;
    }
}

// ======= fused CSR finish: hist + scan + rowptr + dinv + xs + scatter ====
// xs rows padded to 8 floats (32B): one aligned 64B-line touch per gather.
__global__ void fillB2(const unsigned* __restrict__ stage,
                       const int* __restrict__ bcur,
                       int* __restrict__ rowptr, float* __restrict__ dinv,
                       int* __restrict__ csrs,
                       const float* __restrict__ x, float* __restrict__ xs,
                       int n, int e) {
    __shared__ int ldeg[256];
    __shared__ int loff[256];
    __shared__ int bstart;
    int p = blockIdx.x;
    int t = threadIdx.x;
    int lo = bucket_lo(p, n), hi = bucket_lo(p + 1, n);
    int nloc = hi - lo;                           // <= 196

    // ---- bucketStart[p] = sum of counts of buckets < p ----
    {
        int acc = 0;
        for (int k = t; k < p; k += 256) acc += bcur[k] - k * BCAP;
        ldeg[t] = acc;
        __syncthreads();
        for (int off = 128; off > 0; off >>= 1) {
            if (t < off) ldeg[t] += ldeg[t + off];
            __syncthreads();
        }
        if (t == 0) bstart = ldeg[0];
        __syncthreads();
    }

    // ---- local degree histogram ----
    if (t < 256) ldeg[t] = 0;
    __syncthreads();
    int s0 = p * BCAP, s1 = bcur[p];
    for (int i = s0 + t; i < s1; i += 256)
        atomicAdd(&ldeg[stage[i] & 255u], 1);
    __syncthreads();

    // ---- exclusive scan (256-wide) -> rowptr, dinv, xs, cursors ----
    int v = (t < nloc) ? ldeg[t] : 0;
    loff[t] = v;
    __syncthreads();
    for (int off = 1; off < 256; off <<= 1) {
        int u = (t >= off) ? loff[t - off] : 0;
        __syncthreads();
        loff[t] += u;
        __syncthreads();
    }
    if (t < nloc) {
        int start = bstart + loff[t] - v;         // exclusive
        rowptr[lo + t] = start;
        float dv = rsqrtf((float)v + 1.0f);       // +1 self-loop
        dinv[lo + t] = dv;
        // dinv-folded source rows for layer-1 gather (32B-padded rows)
        const float* xr = x + (size_t)(lo + t) * 5;
        float* xo = xs + (size_t)(lo + t) * 8;
#pragma unroll
        for (int k = 0; k < 5; ++k) xo[k] = xr[k] * dv;
    }
    if (p == NBK - 1 && t == 0) rowptr[n] = e;
    __syncthreads();
    if (t < nloc) ldeg[t] = bstart + loff[t] - v; // reuse as cursors
    __syncthreads();

    // ---- scatter ----
    for (int i = s0 + t; i < s1; i += 256) {
        unsigned pk = stage[i];
        int ldst = (int)(pk & 255u);
        int pos = atomicAdd(&ldeg[ldst], 1);
        csrs[pos] = (int)(pk >> 8);
    }
}

// ---------------- layer-1 aggregate on dinv-folded xs (5-dim, 8-stride) --
// 8-deep batches, masked tail
__global__ void gather5(const int* __restrict__ rowptr,
                        const int* __restrict__ csrs,
                        const float* __restrict__ dinv,
                        const float* __restrict__ xs,
                        float* __restrict__ z, int n) {
    int i = blockIdx.x * blockDim.x + threadIdx.x;
    if (i >= n) return;
    const float* xr = xs + (size_t)i * 8;
    float4 x4 = *(const float4*)(xr);
    float a0 = x4.x, a1 = x4.y, a2 = x4.z, a3 = x4.w, a4 = xr[4];
    int j = rowptr[i], end = rowptr[i + 1], e1 = end - 1;
    for (; j < end; j += 8) {
        int s[8]; float m[8];
#pragma unroll
        for (int k = 0; k < 8; ++k) {
            int jj = j + k;
            s[k] = csrs[jj <= e1 ? jj : e1];
            m[k] = (jj < end) ? 1.0f : 0.0f;
        }
        float4 r4[8]; float r1[8];
#pragma unroll
        for (int k = 0; k < 8; ++k) {
            const float* r = xs + (size_t)s[k] * 8;
            r4[k] = *(const float4*)(r);
            r1[k] = r[4];
        }
#pragma unroll
        for (int k = 0; k < 8; ++k) {
            a0 = fmaf(m[k], r4[k].x, a0);
            a1 = fmaf(m[k], r4[k].y, a1);
            a2 = fmaf(m[k], r4[k].z, a2);
            a3 = fmaf(m[k], r4[k].w, a3);
            a4 = fmaf(m[k], r1[k], a4);
        }
    }
    float di = dinv[i];
    float* zr = z + (size_t)i * 5;
    zr[0] = a0 * di; zr[1] = a1 * di; zr[2] = a2 * di;
    zr[3] = a3 * di; zr[4] = a4 * di;
}

// ---- transform epilogue: bias/relu/scale + fp32 or packed-bf16 store ----
template<int DOUT, bool BR, bool SCALE, bool OUTBF>
static __device__ __forceinline__ void emit(float o[8], const float* b, int c,
                                            float dsc, void* out, int i) {
    if (BR) {
        float4 b0 = *(const float4*)(b + c * 8);
        float4 b1 = *(const float4*)(b + c * 8 + 4);
        o[0] = fmaxf(o[0] + b0.x, 0.f); o[1] = fmaxf(o[1] + b0.y, 0.f);
        o[2] = fmaxf(o[2] + b0.z, 0.f); o[3] = fmaxf(o[3] + b0.w, 0.f);
        o[4] = fmaxf(o[4] + b1.x, 0.f); o[5] = fmaxf(o[5] + b1.y, 0.f);
        o[6] = fmaxf(o[6] + b1.z, 0.f); o[7] = fmaxf(o[7] + b1.w, 0.f);
    }
    if (SCALE) {
#pragma unroll
        for (int q = 0; q < 8; ++q) o[q] *= dsc;
    }
    if (OUTBF) {
        uint4 pk;
        pk.x = packbf(o[0], o[1]); pk.y = packbf(o[2], o[3]);
        pk.z = packbf(o[4], o[5]); pk.w = packbf(o[6], o[7]);
        *(uint4*)((unsigned*)out + (size_t)i * (DOUT / 2) + c * 4) = pk;
    } else {
        float* op = (float*)out + (size_t)i * DOUT + c * 8;
        float4 o0 = {o[0], o[1], o[2], o[3]};
        float4 o1 = {o[4], o[5], o[6], o[7]};
        *(float4*)(op) = o0;
        *(float4*)(op + 4) = o1;
    }
}

// ---- K=5 fp32-input transform (layer 1) --------------------------------
template<int DOUT, bool BR, bool SCALE, bool OUTBF, int NODES>
__global__ void transformB5(const float* __restrict__ xin,
                            const float* __restrict__ W,
                            const float* __restrict__ b,
                            const float* __restrict__ dinv,
                            void* __restrict__ out, int n) {
    const int C = DOUT / 8;
    int tid = blockIdx.x * blockDim.x + threadIdx.x;
    int grp = tid / C;
    int c = tid % C;
    int i0 = grp * NODES;
    if (i0 >= n) return;
    float r[NODES][5];
#pragma unroll
    for (int nn = 0; nn < NODES; ++nn) {
        int idx = i0 + nn < n ? i0 + nn : n - 1;
        const float* row = xin + (size_t)idx * 5;
#pragma unroll
        for (int k = 0; k < 5; ++k) r[nn][k] = row[k];
    }
    float acc[NODES][8];
#pragma unroll
    for (int nn = 0; nn < NODES; ++nn)
#pragma unroll
        for (int q = 0; q < 8; ++q) acc[nn][q] = 0.0f;
#pragma unroll
    for (int k = 0; k < 5; ++k) {
        const float* wp = W + (size_t)k * DOUT + c * 8;
        float4 w0 = *(const float4*)(wp);
        float4 w1 = *(const float4*)(wp + 4);
#pragma unroll
        for (int nn = 0; nn < NODES; ++nn) {
            float v = r[nn][k];
            acc[nn][0] = fmaf(v, w0.x, acc[nn][0]);
            acc[nn][1] = fmaf(v, w0.y, acc[nn][1]);
            acc[nn][2] = fmaf(v, w0.z, acc[nn][2]);
            acc[nn][3] = fmaf(v, w0.w, acc[nn][3]);
            acc[nn][4] = fmaf(v, w1.x, acc[nn][4]);
            acc[nn][5] = fmaf(v, w1.y, acc[nn][5]);
            acc[nn][6] = fmaf(v, w1.z, acc[nn][6]);
            acc[nn][7] = fmaf(v, w1.w, acc[nn][7]);
        }
    }
#pragma unroll
    for (int nn = 0; nn < NODES; ++nn) {
        if (i0 + nn >= n) break;
        float dsc = SCALE ? dinv[i0 + nn] : 1.0f;
        emit<DOUT, BR, SCALE, OUTBF>(acc[nn], b, c, dsc, out, i0 + nn);
    }
}

// ------- 64-dim gather from bf16 table (dinv pre-folded into table) ------
// 16 outstanding row loads; requires caller kernel to allow >=130 VGPRs
static __device__ __forceinline__ void gather_row(const int* __restrict__ rowptr,
                                                  const int* __restrict__ csrs,
                                                  const unsigned* __restrict__ g,
                                                  int i, int c, float o[8]) {
    uint4 sv = *(const uint4*)(g + (size_t)i * 32 + c * 4);
    float a[4][8];
#pragma unroll
    for (int q = 0; q < 8; ++q) { a[1][q] = 0.f; a[2][q] = 0.f; a[3][q] = 0.f; }
    a[0][0] = blo(sv.x); a[0][1] = bhi(sv.x); a[0][2] = blo(sv.y); a[0][3] = bhi(sv.y);
    a[0][4] = blo(sv.z); a[0][5] = bhi(sv.z); a[0][6] = blo(sv.w); a[0][7] = bhi(sv.w);
    int j = rowptr[i], end = rowptr[i + 1];
    for (; j + 16 <= end; j += 16) {
        uint4 v[16];
#pragma unroll
        for (int k = 0; k < 16; ++k)
            v[k] = *(const uint4*)(g + (size_t)csrs[j + k] * 32 + c * 4);
#pragma unroll
        for (int k = 0; k < 16; ++k) {
            float* aa = a[k & 3];
            aa[0] += blo(v[k].x); aa[1] += bhi(v[k].x);
            aa[2] += blo(v[k].y); aa[3] += bhi(v[k].y);
            aa[4] += blo(v[k].z); aa[5] += bhi(v[k].z);
            aa[6] += blo(v[k].w); aa[7] += bhi(v[k].w);
        }
    }
    if (j < end) {
        int e1 = end - 1;
        uint4 v[16]; float mm[16];
#pragma unroll
        for (int k = 0; k < 16; ++k) {
            int jj = j + k;
            int sx = csrs[jj <= e1 ? jj : e1];
            mm[k] = (jj < end) ? 1.0f : 0.0f;
            v[k] = *(const uint4*)(g + (size_t)sx * 32 + c * 4);
        }
#pragma unroll
        for (int k = 0; k < 16; ++k) {
            float* aa = a[k & 3];
            float m = mm[k];
            aa[0] = fmaf(m, blo(v[k].x), aa[0]); aa[1] = fmaf(m, bhi(v[k].x), aa[1]);
            aa[2] = fmaf(m, blo(v[k].y), aa[2]); aa[3] = fmaf(m, bhi(v[k].y), aa[3]);
            aa[4] = fmaf(m, blo(v[k].z), aa[4]); aa[5] = fmaf(m, bhi(v[k].z), aa[5]);
            aa[6] = fmaf(m, blo(v[k].w), aa[6]); aa[7] = fmaf(m, bhi(v[k].w), aa[7]);
        }
    }
#pragma unroll
    for (int q = 0; q < 8; ++q)
        o[q] = (a[0][q] + a[1][q]) + (a[2][q] + a[3][q]);
}

// BR: +bias+relu.  OUTBF: pack bf16 rows [n][32]; else fp32 [n][64].
// launch_bounds(256,2): 2 blk/CU, VGPR cap 256 -> no spill for 16-deep.
template<bool BR, bool OUTBF>
__global__ __launch_bounds__(256, 2)
void gatherBF(const int* __restrict__ rowptr,
              const int* __restrict__ csrs,
              const float* __restrict__ dinv,
              const float* __restrict__ b,
              const unsigned* __restrict__ g,   // [n][32] packed bf16
              void* __restrict__ z, int n) {
    int tid = blockIdx.x * blockDim.x + threadIdx.x;
    int i = tid >> 3;
    int c = tid & 7;
    if (i >= n) return;
    float o[8];
    gather_row(rowptr, csrs, g, i, c, o);
    float di = dinv[i];
#pragma unroll
    for (int q = 0; q < 8; ++q) o[q] *= di;
    if (BR) {
        float4 b0 = *(const float4*)(b + c * 8);
        float4 b1 = *(const float4*)(b + c * 8 + 4);
        o[0] = fmaxf(o[0] + b0.x, 0.f); o[1] = fmaxf(o[1] + b0.y, 0.f);
        o[2] = fmaxf(o[2] + b0.z, 0.f); o[3] = fmaxf(o[3] + b0.w, 0.f);
        o[4] = fmaxf(o[4] + b1.x, 0.f); o[5] = fmaxf(o[5] + b1.y, 0.f);
        o[6] = fmaxf(o[6] + b1.z, 0.f); o[7] = fmaxf(o[7] + b1.w, 0.f);
    }
    if (OUTBF) {
        uint4 pk;
        pk.x = packbf(o[0], o[1]); pk.y = packbf(o[2], o[3]);
        pk.z = packbf(o[4], o[5]); pk.w = packbf(o[6], o[7]);
        *(uint4*)((unsigned*)z + (size_t)i * 32 + c * 4) = pk;
    } else {
        float* zp = (float*)z + (size_t)i * 64 + c * 8;
        float4 z0 = {o[0], o[1], o[2], o[3]};
        float4 z1 = {o[4], o[5], o[6], o[7]};
        *(float4*)(zp) = z0;
        *(float4*)(zp + 4) = z1;
    }
}

// ===== fused layer-2+3: gather(h1bf)->z2(LDS,fp32) ->W2+b2+relu->
//       h2(LDS,bf16) ->W3*dinv -> t3bf.  96 nodes / 256 threads.
// launch_bounds(256,3): LDS caps at 3 blk/CU anyway; VGPR cap ~168. =====
__global__ __launch_bounds__(256, 3)
void layer23(const int* __restrict__ rowptr,
             const int* __restrict__ csrs,
             const float* __restrict__ dinv,
             const float* __restrict__ b2v,
             const unsigned* __restrict__ g,    // h1bf [n][32]
             const float* __restrict__ W2,      // [64][128]
             const float* __restrict__ W3,      // [128][64]
             unsigned* __restrict__ t3, int n) {
    __shared__ float    z2s[FBN][68];   // fp32, stride 68 (quad-stride 17)
    __shared__ unsigned h2s[FBN][68];   // 64 uints bf16 + pad
    int t = threadIdx.x;
    int base = blockIdx.x * FBN;

    // ---- phase 1: gather z2 rows; 3 passes x 32 nodes, 8 lanes/node ----
    {
        int nd = t >> 3, c = t & 7;
        for (int pass = 0; pass < 3; ++pass) {
            int lr = pass * 32 + nd;
            int i = base + lr;
            if (i < n) {
                float o[8];
                gather_row(rowptr, csrs, g, i, c, o);
                float di = dinv[i];
                float4 z0 = {o[0] * di, o[1] * di, o[2] * di, o[3] * di};
                float4 z1 = {o[4] * di, o[5] * di, o[6] * di, o[7] * di};
                *(float4*)&z2s[lr][c * 8] = z0;
                *(float4*)&z2s[lr][c * 8 + 4] = z1;
            }
        }
    }
    __syncthreads();

    // ---- phase 2: 64->128 + bias + relu -> bf16 h2s (6 nodes/thread) ----
    {
        int c2 = t & 15;             // outs c2*8..+8 (of 128)
        int ng = t >> 4;             // 0..15; nodes ng + 16*nn
        float acc[6][8];
#pragma unroll
        for (int nn = 0; nn < 6; ++nn)
#pragma unroll
            for (int q = 0; q < 8; ++q) acc[nn][q] = 0.0f;
        for (int k0 = 0; k0 < 64; k0 += 4) {
            float4 r[6];
#pragma unroll
            for (int nn = 0; nn < 6; ++nn)
                r[nn] = *(const float4*)&z2s[ng + 16 * nn][k0];
#pragma unroll
            for (int kk = 0; kk < 4; ++kk) {
                const float* wp = W2 + (size_t)(k0 + kk) * 128 + c2 * 8;
                float4 w0 = *(const float4*)(wp);
                float4 w1 = *(const float4*)(wp + 4);
#pragma unroll
                for (int nn = 0; nn < 6; ++nn) {
                    float v = (&r[nn].x)[kk];
                    acc[nn][0] = fmaf(v, w0.x, acc[nn][0]);
                    acc[nn][1] = fmaf(v, w0.y, acc[nn][1]);
                    acc[nn][2] = fmaf(v, w0.z, acc[nn][2]);
                    acc[nn][3] = fmaf(v, w0.w, acc[nn][3]);
                    acc[nn][4] = fmaf(v, w1.x, acc[nn][4]);
                    acc[nn][5] = fmaf(v, w1.y, acc[nn][5]);
                    acc[nn][6] = fmaf(v, w1.z, acc[nn][6]);
                    acc[nn][7] = fmaf(v, w1.w, acc[nn][7]);
                }
            }
        }
        float4 b0 = *(const float4*)(b2v + c2 * 8);
        float4 b1 = *(const float4*)(b2v + c2 * 8 + 4);
#pragma unroll
        for (int nn = 0; nn < 6; ++nn) {
            float o[8];
            o[0] = fmaxf(acc[nn][0] + b0.x, 0.f);
            o[1] = fmaxf(acc[nn][1] + b0.y, 0.f);
            o[2] = fmaxf(acc[nn][2] + b0.z, 0.f);
            o[3] = fmaxf(acc[nn][3] + b0.w, 0.f);
            o[4] = fmaxf(acc[nn][4] + b1.x, 0.f);
            o[5] = fmaxf(acc[nn][5] + b1.y, 0.f);
            o[6] = fmaxf(acc[nn][6] + b1.z, 0.f);
            o[7] = fmaxf(acc[nn][7] + b1.w, 0.f);
            uint4 pk;
            pk.x = packbf(o[0], o[1]); pk.y = packbf(o[2], o[3]);
            pk.z = packbf(o[4], o[5]); pk.w = packbf(o[6], o[7]);
            *(uint4*)&h2s[ng + 16 * nn][c2 * 4] = pk;
        }
    }
    __syncthreads();

    // ---- phase 3: bf16 128->64, *dinv -> t3 (3 nodes/thread) ----
    {
        int c3 = t & 7;              // outs c3*8..+8 (of 64)
        int ng = t >> 3;             // 0..31; nodes ng + 32*nn
        float acc[3][8];
#pragma unroll
        for (int nn = 0; nn < 3; ++nn)
#pragma unroll
            for (int q = 0; q < 8; ++q) acc[nn][q] = 0.0f;
        for (int k0 = 0; k0 < 128; k0 += 8) {
            uint4 r[3];
#pragma unroll
            for (int nn = 0; nn < 3; ++nn)
                r[nn] = *(const uint4*)&h2s[ng + 32 * nn][k0 >> 1];
#pragma unroll
            for (int kk = 0; kk < 8; ++kk) {
                const float* wp = W3 + (size_t)(k0 + kk) * 64 + c3 * 8;
                float4 w0 = *(const float4*)(wp);
                float4 w1 = *(const float4*)(wp + 4);
#pragma unroll
                for (int nn = 0; nn < 3; ++nn) {
                    unsigned u = (&r[nn].x)[kk >> 1];
                    float v = (kk & 1) ? bhi(u) : blo(u);
                    acc[nn][0] = fmaf(v, w0.x, acc[nn][0]);
                    acc[nn][1] = fmaf(v, w0.y, acc[nn][1]);
                    acc[nn][2] = fmaf(v, w0.z, acc[nn][2]);
                    acc[nn][3] = fmaf(v, w0.w, acc[nn][3]);
                    acc[nn][4] = fmaf(v, w1.x, acc[nn][4]);
                    acc[nn][5] = fmaf(v, w1.y, acc[nn][5]);
                    acc[nn][6] = fmaf(v, w1.z, acc[nn][6]);
                    acc[nn][7] = fmaf(v, w1.w, acc[nn][7]);
                }
            }
        }
#pragma unroll
        for (int nn = 0; nn < 3; ++nn) {
            int i = base + ng + 32 * nn;
            if (i < n) {
                float ds = dinv[i];
                uint4 pk;
                pk.x = packbf(acc[nn][0] * ds, acc[nn][1] * ds);
                pk.y = packbf(acc[nn][2] * ds, acc[nn][3] * ds);
                pk.z = packbf(acc[nn][4] * ds, acc[nn][5] * ds);
                pk.w = packbf(acc[nn][6] * ds, acc[nn][7] * ds);
                *(uint4*)(t3 + (size_t)i * 32 + c3 * 4) = pk;
            }
        }
    }
}

// ------- pooling + FC + sigmoid: 4 waves per graph, bf16 h3 rows --------
__global__ void pool(const unsigned* __restrict__ h3,  // [n][32] packed bf16
                     const int* __restrict__ batch,
                     const float* __restrict__ Wfc, const float* __restrict__ bfc,
                     float* __restrict__ out, int n) {
    int g = blockIdx.x;
    int lane = threadIdx.x & 63;
    int w = threadIdx.x >> 6;  // 0..3
    int lo = 0, hi = n;
    while (lo < hi) { int m = (lo + hi) >> 1; if (batch[m] < g) lo = m + 1; else hi = m; }
    int start = lo;
    hi = n;
    while (lo < hi) { int m = (lo + hi) >> 1; if (batch[m] < g + 1) lo = m + 1; else hi = m; }
    int end = lo;
    int ui = lane >> 1;            // uint index within row
    bool hs = lane & 1;            // hi/lo half
    float a0 = 0.f, a1 = 0.f, a2 = 0.f, a3 = 0.f;
    int m = start + w;
    for (; m + 12 < end; m += 16) {
        unsigned u0 = h3[(size_t)m * 32 + ui];
        unsigned u1 = h3[(size_t)(m + 4) * 32 + ui];
        unsigned u2 = h3[(size_t)(m + 8) * 32 + ui];
        unsigned u3 = h3[(size_t)(m + 12) * 32 + ui];
        a0 += hs ? bhi(u0) : blo(u0);
        a1 += hs ? bhi(u1) : blo(u1);
        a2 += hs ? bhi(u2) : blo(u2);
        a3 += hs ? bhi(u3) : blo(u3);
    }
    for (; m < end; m += 4) {
        unsigned u0 = h3[(size_t)m * 32 + ui];
        a0 += hs ? bhi(u0) : blo(u0);
    }
    __shared__ float sh[4][64];
    sh[w][lane] = (a0 + a1) + (a2 + a3);
    __syncthreads();
    if (w == 0) {
        float v = (sh[0][lane] + sh[1][lane]) + (sh[2][lane] + sh[3][lane]);
        float cnt = (float)(end - start);
        v = (v / fmaxf(cnt, 1.0f)) * Wfc[lane];
#pragma unroll
        for (int off = 32; off > 0; off >>= 1) v += __shfl_down(v, off, 64);
        if (lane == 0) out[g] = 1.0f / (1.0f + expf(-(v + bfc[0])));
    }
}

static inline int cdiv(long long a, int b) { return (int)((a + b - 1) / b); }

extern "C" void kernel_launch(void* const* d_in, const int* in_sizes, int n_in,
                              void* d_out, int out_size, void* d_ws, size_t ws_size,
                              hipStream_t stream) {
    const float* x   = (const float*)d_in[0];
    const int*   ei  = (const int*)d_in[1];
    const int*   bat = (const int*)d_in[2];
    const float* W1  = (const float*)d_in[3];
    const float* b1  = (const float*)d_in[4];
    const float* W2  = (const float*)d_in[5];
    const float* b2  = (const float*)d_in[6];
    const float* W3  = (const float*)d_in[7];
    const float* b3  = (const float*)d_in[8];
    const float* Wfc = (const float*)d_in[9];
    const float* bfc = (const float*)d_in[10];
    float* out = (float*)d_out;

    const int N = in_sizes[0] / 5;   // 100000
    const int E = in_sizes[1] / 2;   // 1600000
    const int* src = ei;
    const int* ds  = ei + E;

    // ---- workspace layout: every buffer 256B-aligned so bf16 feature
    //      rows (128B) never straddle cache lines on random gathers ----
    char* wsb = (char*)d_ws;
    size_t off = 0;
#define A256(X) (((X) + (size_t)255) & ~(size_t)255)
    float* dinv   = (float*)(wsb + off); off = A256(off + (size_t)N * 4);
    int*   rowptr = (int*)(wsb + off);   off = A256(off + (size_t)(N + 4) * 4);
    int*   bcur   = (int*)(wsb + off);   off = A256(off + (size_t)NBK * 4);
    int*   csrs   = (int*)(wsb + off);   off = A256(off + (size_t)E * 4);
    float* A      = (float*)(wsb + off); off = A256(off + (size_t)N * 128 * 4);
    float* B      = (float*)(wsb + off);
#undef A256
    // aliases (strictly sequential lifetimes):
    unsigned* stage = (unsigned*)A;              // 7.34MB, dead after fillB2
    float*    xs    = A + (size_t)(1 << 21);     // N*8 fp32 @ +8MB (past stage)
    float*    z1    = A;                         // N*5 fp32 (disjoint from xs)
    unsigned* h1bf  = (unsigned*)B;              // N*32 (bf16, dinv-folded)
    unsigned* t3bf  = (unsigned*)A;              // N*32 bf16 (z1/xs dead)
    unsigned* h3bf  = (unsigned*)B;              // N*32 bf16 (h1bf dead)

    const int Blk = 256;

    // ---- CSR build: bucket sort -> fused hist/scan/dinv/xs/scatter ----
    zero_bcur<<<2, 256, 0, stream>>>(bcur);
    bucketA<<<256, 256, 0, stream>>>(src, ds, bcur, stage, E, N);
    fillB2<<<NBK, 256, 0, stream>>>(stage, bcur, rowptr, dinv, csrs, x, xs, N, E);

    // ---- layer 1: aggregate folded xs (5-dim); 5->64 +bias+relu ->bf16*dinv
    gather5<<<cdiv(N, Blk), Blk, 0, stream>>>(rowptr, csrs, dinv, xs, z1, N);
    transformB5<64, true, true, true, 2>
        <<<cdiv((long long)cdiv(N, 2) * 8, Blk), Blk, 0, stream>>>(
        z1, W1, b1, dinv, h1bf, N);

    // ---- fused layers 2+3: gather->T2(relu)->T3(*dinv) -> t3bf ----
    layer23<<<cdiv(N, FBN), 256, 0, stream>>>(
        rowptr, csrs, dinv, b2, h1bf, W2, W3, t3bf, N);

    // ---- layer 3 aggregate: gather t3bf +bias+relu -> bf16 h3 ----
    gatherBF<true, true><<<cdiv((long long)N * 8, Blk), Blk, 0, stream>>>(
        rowptr, csrs, dinv, b3, t3bf, h3bf, N);

    // ---- pooling + FC head ----
    pool<<<NG, 256, 0, stream>>>(h3bf, bat, Wfc, bfc, out, N);
}

// Round 14
// 277.787 us; speedup vs baseline: 1.6407x; 1.0563x over previous
//
#include <hip/hip_runtime.h>
#include <math.h>

#define NG 256
#define NBK 512          // sort buckets
#define BCAP 3584        // per-bucket staging capacity (mean 3125, +8 sigma)
#define FBN 96           // nodes per fused layer23 block (52KB LDS, 3 blocks/CU)
// Measured design space (final): FBN96/fp32-z2 fused layer23 + 8-deep gather
// = 94us, pipeline 279us BEST. Regressions: FBN64=111us (ILP cut); bf16-z2
// 4blk=105us (L2 thrash); split=97us transform alone; atomic pool=5x;
// 16-deep gather spills at any launch_bounds (R12: 177MB scratch, R13:
// VGPR 84 + 39MB scratch) — deeper MLP needs inline-asm vmcnt control.

static __device__ __forceinline__ int bucket_lo(int p, int n) {
    return (int)(((long long)p * n + NBK - 1) / NBK);   // ceil(p*n/NBK)
}

// ---- bf16 helpers (tables stored as packed pairs in uint) ----
static __device__ __forceinline__ float blo(unsigned u) {
    return __uint_as_float(u << 16);
}
static __device__ __forceinline__ float bhi(unsigned u) {
    return __uint_as_float(u & 0xFFFF0000u);
}
static __device__ __forceinline__ unsigned packbf(float a, float b) {
    unsigned ua = __float_as_uint(a);
    ua = (ua + 0x7FFFu + ((ua >> 16) & 1u)) >> 16;          // RNE, low half
    unsigned ub = __float_as_uint(b);
    ub = (ub + 0x7FFFu + ((ub >> 16) & 1u)) & 0xFFFF0000u;  // RNE, high half
    return ua | ub;
}

// ---------------- bucket cursor init ----------------
__global__ void zero_bcur(int* bcur) {
    int i = blockIdx.x * blockDim.x + threadIdx.x;
    if (i < NBK) bcur[i] = i * BCAP;
}

// ------- phase A: bucket edges by dst; staged record = (src<<8)|local_dst --
__global__ void bucketA(const int* __restrict__ src, const int* __restrict__ dst,
                        int* bcur, unsigned* stage, int e, int n) {
    __shared__ int cnt[NBK];
    __shared__ int base[NBK];
    int nb = gridDim.x;
    int c0 = (int)((long long)blockIdx.x * e / nb);
    int c1 = (int)((long long)(blockIdx.x + 1) * e / nb);
    for (int k = threadIdx.x; k < NBK; k += blockDim.x) cnt[k] = 0;
    __syncthreads();
    for (int i = c0 + threadIdx.x; i < c1; i += blockDim.x) {
        int d = dst[i];
        int p = (int)((long long)d * NBK / n);
        atomicAdd(&cnt[p], 1);
    }
    __syncthreads();
    for (int k = threadIdx.x; k < NBK; k += blockDim.x)
        base[k] = atomicAdd(&bcur[k], cnt[k]);
    __syncthreads();
    for (int k = threadIdx.x; k < NBK; k += blockDim.x) cnt[k] = 0;
    __syncthreads();
    for (int i = c0 + threadIdx.x; i < c1; i += blockDim.x) {
        int s = src[i], d = dst[i];
        int p = (int)((long long)d * NBK / n);
        int ldst = d - bucket_lo(p, n);           // < 196, fits 8 bits
        int lp = atomicAdd(&cnt[p], 1);
        stage[base[p] + lp] = ((unsigned)s << 8) | (unsigned)ldst;
    }
}

// ======= fused CSR finish: hist + scan + rowptr + dinv + xs + scatter ====
// xs rows padded to 8 floats (32B): one aligned 64B-line touch per gather.
__global__ void fillB2(const unsigned* __restrict__ stage,
                       const int* __restrict__ bcur,
                       int* __restrict__ rowptr, float* __restrict__ dinv,
                       int* __restrict__ csrs,
                       const float* __restrict__ x, float* __restrict__ xs,
                       int n, int e) {
    __shared__ int ldeg[256];
    __shared__ int loff[256];
    __shared__ int bstart;
    int p = blockIdx.x;
    int t = threadIdx.x;
    int lo = bucket_lo(p, n), hi = bucket_lo(p + 1, n);
    int nloc = hi - lo;                           // <= 196

    // ---- bucketStart[p] = sum of counts of buckets < p ----
    {
        int acc = 0;
        for (int k = t; k < p; k += 256) acc += bcur[k] - k * BCAP;
        ldeg[t] = acc;
        __syncthreads();
        for (int off = 128; off > 0; off >>= 1) {
            if (t < off) ldeg[t] += ldeg[t + off];
            __syncthreads();
        }
        if (t == 0) bstart = ldeg[0];
        __syncthreads();
    }

    // ---- local degree histogram ----
    if (t < 256) ldeg[t] = 0;
    __syncthreads();
    int s0 = p * BCAP, s1 = bcur[p];
    for (int i = s0 + t; i < s1; i += 256)
        atomicAdd(&ldeg[stage[i] & 255u], 1);
    __syncthreads();

    // ---- exclusive scan (256-wide) -> rowptr, dinv, xs, cursors ----
    int v = (t < nloc) ? ldeg[t] : 0;
    loff[t] = v;
    __syncthreads();
    for (int off = 1; off < 256; off <<= 1) {
        int u = (t >= off) ? loff[t - off] : 0;
        __syncthreads();
        loff[t] += u;
        __syncthreads();
    }
    if (t < nloc) {
        int start = bstart + loff[t] - v;         // exclusive
        rowptr[lo + t] = start;
        float dv = rsqrtf((float)v + 1.0f);       // +1 self-loop
        dinv[lo + t] = dv;
        // dinv-folded source rows for layer-1 gather (32B-padded rows)
        const float* xr = x + (size_t)(lo + t) * 5;
        float* xo = xs + (size_t)(lo + t) * 8;
#pragma unroll
        for (int k = 0; k < 5; ++k) xo[k] = xr[k] * dv;
    }
    if (p == NBK - 1 && t == 0) rowptr[n] = e;
    __syncthreads();
    if (t < nloc) ldeg[t] = bstart + loff[t] - v; // reuse as cursors
    __syncthreads();

    // ---- scatter ----
    for (int i = s0 + t; i < s1; i += 256) {
        unsigned pk = stage[i];
        int ldst = (int)(pk & 255u);
        int pos = atomicAdd(&ldeg[ldst], 1);
        csrs[pos] = (int)(pk >> 8);
    }
}

// ---------------- layer-1 aggregate on dinv-folded xs (5-dim, 8-stride) --
// 8-deep batches, masked tail
__global__ void gather5(const int* __restrict__ rowptr,
                        const int* __restrict__ csrs,
                        const float* __restrict__ dinv,
                        const float* __restrict__ xs,
                        float* __restrict__ z, int n) {
    int i = blockIdx.x * blockDim.x + threadIdx.x;
    if (i >= n) return;
    const float* xr = xs + (size_t)i * 8;
    float4 x4 = *(const float4*)(xr);
    float a0 = x4.x, a1 = x4.y, a2 = x4.z, a3 = x4.w, a4 = xr[4];
    int j = rowptr[i], end = rowptr[i + 1], e1 = end - 1;
    for (; j < end; j += 8) {
        int s[8]; float m[8];
#pragma unroll
        for (int k = 0; k < 8; ++k) {
            int jj = j + k;
            s[k] = csrs[jj <= e1 ? jj : e1];
            m[k] = (jj < end) ? 1.0f : 0.0f;
        }
        float4 r4[8]; float r1[8];
#pragma unroll
        for (int k = 0; k < 8; ++k) {
            const float* r = xs + (size_t)s[k] * 8;
            r4[k] = *(const float4*)(r);
            r1[k] = r[4];
        }
#pragma unroll
        for (int k = 0; k < 8; ++k) {
            a0 = fmaf(m[k], r4[k].x, a0);
            a1 = fmaf(m[k], r4[k].y, a1);
            a2 = fmaf(m[k], r4[k].z, a2);
            a3 = fmaf(m[k], r4[k].w, a3);
            a4 = fmaf(m[k], r1[k], a4);
        }
    }
    float di = dinv[i];
    float* zr = z + (size_t)i * 5;
    zr[0] = a0 * di; zr[1] = a1 * di; zr[2] = a2 * di;
    zr[3] = a3 * di; zr[4] = a4 * di;
}

// ---- transform epilogue: bias/relu/scale + fp32 or packed-bf16 store ----
template<int DOUT, bool BR, bool SCALE, bool OUTBF>
static __device__ __forceinline__ void emit(float o[8], const float* b, int c,
                                            float dsc, void* out, int i) {
    if (BR) {
        float4 b0 = *(const float4*)(b + c * 8);
        float4 b1 = *(const float4*)(b + c * 8 + 4);
        o[0] = fmaxf(o[0] + b0.x, 0.f); o[1] = fmaxf(o[1] + b0.y, 0.f);
        o[2] = fmaxf(o[2] + b0.z, 0.f); o[3] = fmaxf(o[3] + b0.w, 0.f);
        o[4] = fmaxf(o[4] + b1.x, 0.f); o[5] = fmaxf(o[5] + b1.y, 0.f);
        o[6] = fmaxf(o[6] + b1.z, 0.f); o[7] = fmaxf(o[7] + b1.w, 0.f);
    }
    if (SCALE) {
#pragma unroll
        for (int q = 0; q < 8; ++q) o[q] *= dsc;
    }
    if (OUTBF) {
        uint4 pk;
        pk.x = packbf(o[0], o[1]); pk.y = packbf(o[2], o[3]);
        pk.z = packbf(o[4], o[5]); pk.w = packbf(o[6], o[7]);
        *(uint4*)((unsigned*)out + (size_t)i * (DOUT / 2) + c * 4) = pk;
    } else {
        float* op = (float*)out + (size_t)i * DOUT + c * 8;
        float4 o0 = {o[0], o[1], o[2], o[3]};
        float4 o1 = {o[4], o[5], o[6], o[7]};
        *(float4*)(op) = o0;
        *(float4*)(op + 4) = o1;
    }
}

// ---- K=5 fp32-input transform (layer 1) --------------------------------
template<int DOUT, bool BR, bool SCALE, bool OUTBF, int NODES>
__global__ void transformB5(const float* __restrict__ xin,
                            const float* __restrict__ W,
                            const float* __restrict__ b,
                            const float* __restrict__ dinv,
                            void* __restrict__ out, int n) {
    const int C = DOUT / 8;
    int tid = blockIdx.x * blockDim.x + threadIdx.x;
    int grp = tid / C;
    int c = tid % C;
    int i0 = grp * NODES;
    if (i0 >= n) return;
    float r[NODES][5];
#pragma unroll
    for (int nn = 0; nn < NODES; ++nn) {
        int idx = i0 + nn < n ? i0 + nn : n - 1;
        const float* row = xin + (size_t)idx * 5;
#pragma unroll
        for (int k = 0; k < 5; ++k) r[nn][k] = row[k];
    }
    float acc[NODES][8];
#pragma unroll
    for (int nn = 0; nn < NODES; ++nn)
#pragma unroll
        for (int q = 0; q < 8; ++q) acc[nn][q] = 0.0f;
#pragma unroll
    for (int k = 0; k < 5; ++k) {
        const float* wp = W + (size_t)k * DOUT + c * 8;
        float4 w0 = *(const float4*)(wp);
        float4 w1 = *(const float4*)(wp + 4);
#pragma unroll
        for (int nn = 0; nn < NODES; ++nn) {
            float v = r[nn][k];
            acc[nn][0] = fmaf(v, w0.x, acc[nn][0]);
            acc[nn][1] = fmaf(v, w0.y, acc[nn][1]);
            acc[nn][2] = fmaf(v, w0.z, acc[nn][2]);
            acc[nn][3] = fmaf(v, w0.w, acc[nn][3]);
            acc[nn][4] = fmaf(v, w1.x, acc[nn][4]);
            acc[nn][5] = fmaf(v, w1.y, acc[nn][5]);
            acc[nn][6] = fmaf(v, w1.z, acc[nn][6]);
            acc[nn][7] = fmaf(v, w1.w, acc[nn][7]);
        }
    }
#pragma unroll
    for (int nn = 0; nn < NODES; ++nn) {
        if (i0 + nn >= n) break;
        float dsc = SCALE ? dinv[i0 + nn] : 1.0f;
        emit<DOUT, BR, SCALE, OUTBF>(acc[nn], b, c, dsc, out, i0 + nn);
    }
}

// ------- 64-dim gather from bf16 table (dinv pre-folded into table) ------
#define ACCA(AA, V) \
    AA[0] += blo(V.x); AA[1] += bhi(V.x); AA[2] += blo(V.y); AA[3] += bhi(V.y); \
    AA[4] += blo(V.z); AA[5] += bhi(V.z); AA[6] += blo(V.w); AA[7] += bhi(V.w);
#define ACCM(AA, V, M) \
    AA[0] = fmaf(M, blo(V.x), AA[0]); AA[1] = fmaf(M, bhi(V.x), AA[1]); \
    AA[2] = fmaf(M, blo(V.y), AA[2]); AA[3] = fmaf(M, bhi(V.y), AA[3]); \
    AA[4] = fmaf(M, blo(V.z), AA[4]); AA[5] = fmaf(M, bhi(V.z), AA[5]); \
    AA[6] = fmaf(M, blo(V.w), AA[6]); AA[7] = fmaf(M, bhi(V.w), AA[7]);

// accumulate one node's 8-feature slice over its edge list into o[8]
// 8-deep unroll (8 loads in flight); masked 8-deep tail
static __device__ __forceinline__ void gather_row(const int* __restrict__ rowptr,
                                                  const int* __restrict__ csrs,
                                                  const unsigned* __restrict__ g,
                                                  int i, int c, float o[8]) {
    uint4 sv = *(const uint4*)(g + (size_t)i * 32 + c * 4);
    float a0[8], a1[8], a2[8], a3[8];
    a0[0] = blo(sv.x); a0[1] = bhi(sv.x); a0[2] = blo(sv.y); a0[3] = bhi(sv.y);
    a0[4] = blo(sv.z); a0[5] = bhi(sv.z); a0[6] = blo(sv.w); a0[7] = bhi(sv.w);
#pragma unroll
    for (int q = 0; q < 8; ++q) { a1[q] = 0.0f; a2[q] = 0.0f; a3[q] = 0.0f; }
    int j = rowptr[i], end = rowptr[i + 1];
    for (; j + 8 <= end; j += 8) {
        uint4 v0 = *(const uint4*)(g + (size_t)csrs[j]     * 32 + c * 4);
        uint4 v1 = *(const uint4*)(g + (size_t)csrs[j + 1] * 32 + c * 4);
        uint4 v2 = *(const uint4*)(g + (size_t)csrs[j + 2] * 32 + c * 4);
        uint4 v3 = *(const uint4*)(g + (size_t)csrs[j + 3] * 32 + c * 4);
        uint4 v4 = *(const uint4*)(g + (size_t)csrs[j + 4] * 32 + c * 4);
        uint4 v5 = *(const uint4*)(g + (size_t)csrs[j + 5] * 32 + c * 4);
        uint4 v6 = *(const uint4*)(g + (size_t)csrs[j + 6] * 32 + c * 4);
        uint4 v7 = *(const uint4*)(g + (size_t)csrs[j + 7] * 32 + c * 4);
        ACCA(a0, v0); ACCA(a1, v1); ACCA(a2, v2); ACCA(a3, v3);
        ACCA(a0, v4); ACCA(a1, v5); ACCA(a2, v6); ACCA(a3, v7);
    }
    if (j < end) {
        int e1 = end - 1;
        int sx[8]; float mm[8];
#pragma unroll
        for (int k = 0; k < 8; ++k) {
            int jj = j + k;
            sx[k] = csrs[jj <= e1 ? jj : e1];
            mm[k] = (jj < end) ? 1.0f : 0.0f;
        }
        uint4 v0 = *(const uint4*)(g + (size_t)sx[0] * 32 + c * 4);
        uint4 v1 = *(const uint4*)(g + (size_t)sx[1] * 32 + c * 4);
        uint4 v2 = *(const uint4*)(g + (size_t)sx[2] * 32 + c * 4);
        uint4 v3 = *(const uint4*)(g + (size_t)sx[3] * 32 + c * 4);
        uint4 v4 = *(const uint4*)(g + (size_t)sx[4] * 32 + c * 4);
        uint4 v5 = *(const uint4*)(g + (size_t)sx[5] * 32 + c * 4);
        uint4 v6 = *(const uint4*)(g + (size_t)sx[6] * 32 + c * 4);
        uint4 v7 = *(const uint4*)(g + (size_t)sx[7] * 32 + c * 4);
        ACCM(a0, v0, mm[0]); ACCM(a1, v1, mm[1]);
        ACCM(a2, v2, mm[2]); ACCM(a3, v3, mm[3]);
        ACCM(a0, v4, mm[4]); ACCM(a1, v5, mm[5]);
        ACCM(a2, v6, mm[6]); ACCM(a3, v7, mm[7]);
    }
#pragma unroll
    for (int q = 0; q < 8; ++q) o[q] = (a0[q] + a1[q]) + (a2[q] + a3[q]);
}

// BR: +bias+relu.  OUTBF: pack bf16 rows [n][32]; else fp32 [n][64].
template<bool BR, bool OUTBF>
__global__ void gatherBF(const int* __restrict__ rowptr,
                         const int* __restrict__ csrs,
                         const float* __restrict__ dinv,
                         const float* __restrict__ b,
                         const unsigned* __restrict__ g,   // [n][32] packed bf16
                         void* __restrict__ z, int n) {
    int tid = blockIdx.x * blockDim.x + threadIdx.x;
    int i = tid >> 3;
    int c = tid & 7;
    if (i >= n) return;
    float o[8];
    gather_row(rowptr, csrs, g, i, c, o);
    float di = dinv[i];
#pragma unroll
    for (int q = 0; q < 8; ++q) o[q] *= di;
    if (BR) {
        float4 b0 = *(const float4*)(b + c * 8);
        float4 b1 = *(const float4*)(b + c * 8 + 4);
        o[0] = fmaxf(o[0] + b0.x, 0.f); o[1] = fmaxf(o[1] + b0.y, 0.f);
        o[2] = fmaxf(o[2] + b0.z, 0.f); o[3] = fmaxf(o[3] + b0.w, 0.f);
        o[4] = fmaxf(o[4] + b1.x, 0.f); o[5] = fmaxf(o[5] + b1.y, 0.f);
        o[6] = fmaxf(o[6] + b1.z, 0.f); o[7] = fmaxf(o[7] + b1.w, 0.f);
    }
    if (OUTBF) {
        uint4 pk;
        pk.x = packbf(o[0], o[1]); pk.y = packbf(o[2], o[3]);
        pk.z = packbf(o[4], o[5]); pk.w = packbf(o[6], o[7]);
        *(uint4*)((unsigned*)z + (size_t)i * 32 + c * 4) = pk;
    } else {
        float* zp = (float*)z + (size_t)i * 64 + c * 8;
        float4 z0 = {o[0], o[1], o[2], o[3]};
        float4 z1 = {o[4], o[5], o[6], o[7]};
        *(float4*)(zp) = z0;
        *(float4*)(zp + 4) = z1;
    }
}

// ===== fused layer-2+3: gather(h1bf)->z2(LDS,fp32) ->W2+b2+relu->
//       h2(LDS,bf16) ->W3*dinv -> t3bf.  96 nodes / 256 threads. =====
__global__ void layer23(const int* __restrict__ rowptr,
                        const int* __restrict__ csrs,
                        const float* __restrict__ dinv,
                        const float* __restrict__ b2v,
                        const unsigned* __restrict__ g,    // h1bf [n][32]
                        const float* __restrict__ W2,      // [64][128]
                        const float* __restrict__ W3,      // [128][64]
                        unsigned* __restrict__ t3, int n) {
    __shared__ float    z2s[FBN][68];   // fp32, stride 68 (quad-stride 17)
    __shared__ unsigned h2s[FBN][68];   // 64 uints bf16 + pad
    int t = threadIdx.x;
    int base = blockIdx.x * FBN;

    // ---- phase 1: gather z2 rows; 3 passes x 32 nodes, 8 lanes/node ----
    {
        int nd = t >> 3, c = t & 7;
        for (int pass = 0; pass < 3; ++pass) {
            int lr = pass * 32 + nd;
            int i = base + lr;
            if (i < n) {
                float o[8];
                gather_row(rowptr, csrs, g, i, c, o);
                float di = dinv[i];
                float4 z0 = {o[0] * di, o[1] * di, o[2] * di, o[3] * di};
                float4 z1 = {o[4] * di, o[5] * di, o[6] * di, o[7] * di};
                *(float4*)&z2s[lr][c * 8] = z0;
                *(float4*)&z2s[lr][c * 8 + 4] = z1;
            }
        }
    }
    __syncthreads();

    // ---- phase 2: 64->128 + bias + relu -> bf16 h2s (6 nodes/thread) ----
    {
        int c2 = t & 15;             // outs c2*8..+8 (of 128)
        int ng = t >> 4;             // 0..15; nodes ng + 16*nn
        float acc[6][8];
#pragma unroll
        for (int nn = 0; nn < 6; ++nn)
#pragma unroll
            for (int q = 0; q < 8; ++q) acc[nn][q] = 0.0f;
        for (int k0 = 0; k0 < 64; k0 += 4) {
            float4 r[6];
#pragma unroll
            for (int nn = 0; nn < 6; ++nn)
                r[nn] = *(const float4*)&z2s[ng + 16 * nn][k0];
#pragma unroll
            for (int kk = 0; kk < 4; ++kk) {
                const float* wp = W2 + (size_t)(k0 + kk) * 128 + c2 * 8;
                float4 w0 = *(const float4*)(wp);
                float4 w1 = *(const float4*)(wp + 4);
#pragma unroll
                for (int nn = 0; nn < 6; ++nn) {
                    float v = (&r[nn].x)[kk];
                    acc[nn][0] = fmaf(v, w0.x, acc[nn][0]);
                    acc[nn][1] = fmaf(v, w0.y, acc[nn][1]);
                    acc[nn][2] = fmaf(v, w0.z, acc[nn][2]);
                    acc[nn][3] = fmaf(v, w0.w, acc[nn][3]);
                    acc[nn][4] = fmaf(v, w1.x, acc[nn][4]);
                    acc[nn][5] = fmaf(v, w1.y, acc[nn][5]);
                    acc[nn][6] = fmaf(v, w1.z, acc[nn][6]);
                    acc[nn][7] = fmaf(v, w1.w, acc[nn][7]);
                }
            }
        }
        float4 b0 = *(const float4*)(b2v + c2 * 8);
        float4 b1 = *(const float4*)(b2v + c2 * 8 + 4);
#pragma unroll
        for (int nn = 0; nn < 6; ++nn) {
            float o[8];
            o[0] = fmaxf(acc[nn][0] + b0.x, 0.f);
            o[1] = fmaxf(acc[nn][1] + b0.y, 0.f);
            o[2] = fmaxf(acc[nn][2] + b0.z, 0.f);
            o[3] = fmaxf(acc[nn][3] + b0.w, 0.f);
            o[4] = fmaxf(acc[nn][4] + b1.x, 0.f);
            o[5] = fmaxf(acc[nn][5] + b1.y, 0.f);
            o[6] = fmaxf(acc[nn][6] + b1.z, 0.f);
            o[7] = fmaxf(acc[nn][7] + b1.w, 0.f);
            uint4 pk;
            pk.x = packbf(o[0], o[1]); pk.y = packbf(o[2], o[3]);
            pk.z = packbf(o[4], o[5]); pk.w = packbf(o[6], o[7]);
            *(uint4*)&h2s[ng + 16 * nn][c2 * 4] = pk;
        }
    }
    __syncthreads();

    // ---- phase 3: bf16 128->64, *dinv -> t3 (3 nodes/thread) ----
    {
        int c3 = t & 7;              // outs c3*8..+8 (of 64)
        int ng = t >> 3;             // 0..31; nodes ng + 32*nn
        float acc[3][8];
#pragma unroll
        for (int nn = 0; nn < 3; ++nn)
#pragma unroll
            for (int q = 0; q < 8; ++q) acc[nn][q] = 0.0f;
        for (int k0 = 0; k0 < 128; k0 += 8) {
            uint4 r[3];
#pragma unroll
            for (int nn = 0; nn < 3; ++nn)
                r[nn] = *(const uint4*)&h2s[ng + 32 * nn][k0 >> 1];
#pragma unroll
            for (int kk = 0; kk < 8; ++kk) {
                const float* wp = W3 + (size_t)(k0 + kk) * 64 + c3 * 8;
                float4 w0 = *(const float4*)(wp);
                float4 w1 = *(const float4*)(wp + 4);
#pragma unroll
                for (int nn = 0; nn < 3; ++nn) {
                    unsigned u = (&r[nn].x)[kk >> 1];
                    float v = (kk & 1) ? bhi(u) : blo(u);
                    acc[nn][0] = fmaf(v, w0.x, acc[nn][0]);
                    acc[nn][1] = fmaf(v, w0.y, acc[nn][1]);
                    acc[nn][2] = fmaf(v, w0.z, acc[nn][2]);
                    acc[nn][3] = fmaf(v, w0.w, acc[nn][3]);
                    acc[nn][4] = fmaf(v, w1.x, acc[nn][4]);
                    acc[nn][5] = fmaf(v, w1.y, acc[nn][5]);
                    acc[nn][6] = fmaf(v, w1.z, acc[nn][6]);
                    acc[nn][7] = fmaf(v, w1.w, acc[nn][7]);
                }
            }
        }
#pragma unroll
        for (int nn = 0; nn < 3; ++nn) {
            int i = base + ng + 32 * nn;
            if (i < n) {
                float ds = dinv[i];
                uint4 pk;
                pk.x = packbf(acc[nn][0] * ds, acc[nn][1] * ds);
                pk.y = packbf(acc[nn][2] * ds, acc[nn][3] * ds);
                pk.z = packbf(acc[nn][4] * ds, acc[nn][5] * ds);
                pk.w = packbf(acc[nn][6] * ds, acc[nn][7] * ds);
                *(uint4*)(t3 + (size_t)i * 32 + c3 * 4) = pk;
            }
        }
    }
}

// ------- pooling + FC + sigmoid: 4 waves per graph, bf16 h3 rows --------
__global__ void pool(const unsigned* __restrict__ h3,  // [n][32] packed bf16
                     const int* __restrict__ batch,
                     const float* __restrict__ Wfc, const float* __restrict__ bfc,
                     float* __restrict__ out, int n) {
    int g = blockIdx.x;
    int lane = threadIdx.x & 63;
    int w = threadIdx.x >> 6;  // 0..3
    int lo = 0, hi = n;
    while (lo < hi) { int m = (lo + hi) >> 1; if (batch[m] < g) lo = m + 1; else hi = m; }
    int start = lo;
    hi = n;
    while (lo < hi) { int m = (lo + hi) >> 1; if (batch[m] < g + 1) lo = m + 1; else hi = m; }
    int end = lo;
    int ui = lane >> 1;            // uint index within row
    bool hs = lane & 1;            // hi/lo half
    float a0 = 0.f, a1 = 0.f, a2 = 0.f, a3 = 0.f;
    int m = start + w;
    for (; m + 12 < end; m += 16) {
        unsigned u0 = h3[(size_t)m * 32 + ui];
        unsigned u1 = h3[(size_t)(m + 4) * 32 + ui];
        unsigned u2 = h3[(size_t)(m + 8) * 32 + ui];
        unsigned u3 = h3[(size_t)(m + 12) * 32 + ui];
        a0 += hs ? bhi(u0) : blo(u0);
        a1 += hs ? bhi(u1) : blo(u1);
        a2 += hs ? bhi(u2) : blo(u2);
        a3 += hs ? bhi(u3) : blo(u3);
    }
    for (; m < end; m += 4) {
        unsigned u0 = h3[(size_t)m * 32 + ui];
        a0 += hs ? bhi(u0) : blo(u0);
    }
    __shared__ float sh[4][64];
    sh[w][lane] = (a0 + a1) + (a2 + a3);
    __syncthreads();
    if (w == 0) {
        float v = (sh[0][lane] + sh[1][lane]) + (sh[2][lane] + sh[3][lane]);
        float cnt = (float)(end - start);
        v = (v / fmaxf(cnt, 1.0f)) * Wfc[lane];
#pragma unroll
        for (int off = 32; off > 0; off >>= 1) v += __shfl_down(v, off, 64);
        if (lane == 0) out[g] = 1.0f / (1.0f + expf(-(v + bfc[0])));
    }
}

static inline int cdiv(long long a, int b) { return (int)((a + b - 1) / b); }

extern "C" void kernel_launch(void* const* d_in, const int* in_sizes, int n_in,
                              void* d_out, int out_size, void* d_ws, size_t ws_size,
                              hipStream_t stream) {
    const float* x   = (const float*)d_in[0];
    const int*   ei  = (const int*)d_in[1];
    const int*   bat = (const int*)d_in[2];
    const float* W1  = (const float*)d_in[3];
    const float* b1  = (const float*)d_in[4];
    const float* W2  = (const float*)d_in[5];
    const float* b2  = (const float*)d_in[6];
    const float* W3  = (const float*)d_in[7];
    const float* b3  = (const float*)d_in[8];
    const float* Wfc = (const float*)d_in[9];
    const float* bfc = (const float*)d_in[10];
    float* out = (float*)d_out;

    const int N = in_sizes[0] / 5;   // 100000
    const int E = in_sizes[1] / 2;   // 1600000
    const int* src = ei;
    const int* ds  = ei + E;

    // ---- workspace layout: every buffer 256B-aligned so bf16 feature
    //      rows (128B) never straddle cache lines on random gathers ----
    char* wsb = (char*)d_ws;
    size_t off = 0;
#define A256(X) (((X) + (size_t)255) & ~(size_t)255)
    float* dinv   = (float*)(wsb + off); off = A256(off + (size_t)N * 4);
    int*   rowptr = (int*)(wsb + off);   off = A256(off + (size_t)(N + 4) * 4);
    int*   bcur   = (int*)(wsb + off);   off = A256(off + (size_t)NBK * 4);
    int*   csrs   = (int*)(wsb + off);   off = A256(off + (size_t)E * 4);
    float* A      = (float*)(wsb + off); off = A256(off + (size_t)N * 128 * 4);
    float* B      = (float*)(wsb + off);
#undef A256
    // aliases (strictly sequential lifetimes):
    unsigned* stage = (unsigned*)A;              // 7.34MB, dead after fillB2
    float*    xs    = A + (size_t)(1 << 21);     // N*8 fp32 @ +8MB (past stage)
    float*    z1    = A;                         // N*5 fp32 (disjoint from xs)
    unsigned* h1bf  = (unsigned*)B;              // N*32 (bf16, dinv-folded)
    unsigned* t3bf  = (unsigned*)A;              // N*32 bf16 (z1/xs dead)
    unsigned* h3bf  = (unsigned*)B;              // N*32 bf16 (h1bf dead)

    const int Blk = 256;

    // ---- CSR build: bucket sort -> fused hist/scan/dinv/xs/scatter ----
    zero_bcur<<<2, 256, 0, stream>>>(bcur);
    bucketA<<<256, 256, 0, stream>>>(src, ds, bcur, stage, E, N);
    fillB2<<<NBK, 256, 0, stream>>>(stage, bcur, rowptr, dinv, csrs, x, xs, N, E);

    // ---- layer 1: aggregate folded xs (5-dim); 5->64 +bias+relu ->bf16*dinv
    gather5<<<cdiv(N, Blk), Blk, 0, stream>>>(rowptr, csrs, dinv, xs, z1, N);
    transformB5<64, true, true, true, 2>
        <<<cdiv((long long)cdiv(N, 2) * 8, Blk), Blk, 0, stream>>>(
        z1, W1, b1, dinv, h1bf, N);

    // ---- fused layers 2+3: gather->T2(relu)->T3(*dinv) -> t3bf ----
    layer23<<<cdiv(N, FBN), 256, 0, stream>>>(
        rowptr, csrs, dinv, b2, h1bf, W2, W3, t3bf, N);

    // ---- layer 3 aggregate: gather t3bf +bias+relu -> bf16 h3 ----
    gatherBF<true, true><<<cdiv((long long)N * 8, Blk), Blk, 0, stream>>>(
        rowptr, csrs, dinv, b3, t3bf, h3bf, N);

    // ---- pooling + FC head ----
    pool<<<NG, 256, 0, stream>>>(h3bf, bat, Wfc, bfc, out, N);
}